// Round 2
// baseline (1340.909 us; speedup 1.0000x reference)
//
#include <hip/hip_runtime.h>

#define NN 100000
#define EE 1600000
#define BB 256
#define IN_F 7
#define HH 128

// ---------------- CSR build ----------------

__global__ void count_deg(const int* __restrict__ ei, int* __restrict__ deg, int e) {
    int i = blockIdx.x * 256 + threadIdx.x;
    if (i < e) atomicAdd(&deg[ei[e + i]], 1);   // dst = ei[E + i]
}

__global__ void scan_partial(const int* __restrict__ deg, int* __restrict__ bsum, int n) {
    __shared__ int sd[256];
    int b = blockIdx.x, t = threadIdx.x;
    int base = b * 1024 + t * 4;
    int s = 0;
    #pragma unroll
    for (int k = 0; k < 4; ++k) { int i = base + k; if (i < n) s += deg[i]; }
    sd[t] = s; __syncthreads();
    for (int off = 128; off > 0; off >>= 1) {
        if (t < off) sd[t] += sd[t + off];
        __syncthreads();
    }
    if (t == 0) bsum[b] = sd[0];
}

__global__ void scan_bsum(int* __restrict__ bsum, int nb) {
    __shared__ int sd[256];
    int t = threadIdx.x;
    int v = (t < nb) ? bsum[t] : 0;
    sd[t] = v; __syncthreads();
    for (int off = 1; off < 256; off <<= 1) {
        int add = (t >= off) ? sd[t - off] : 0;
        __syncthreads();
        sd[t] += add;
        __syncthreads();
    }
    if (t < nb) bsum[t] = sd[t] - v;   // exclusive
}

__global__ void scan_apply(const int* __restrict__ deg, const int* __restrict__ bsum,
                           int* __restrict__ rowptr, int* __restrict__ cursor, int n, int e) {
    __shared__ int sd[256];
    int b = blockIdx.x, t = threadIdx.x;
    int base = b * 1024 + t * 4;
    int v[4]; int s = 0;
    #pragma unroll
    for (int k = 0; k < 4; ++k) { int i = base + k; v[k] = (i < n) ? deg[i] : 0; s += v[k]; }
    sd[t] = s; __syncthreads();
    int mine = s;
    for (int off = 1; off < 256; off <<= 1) {
        int add = (t >= off) ? sd[t - off] : 0;
        __syncthreads();
        sd[t] += add;
        __syncthreads();
    }
    int run = sd[t] - mine + bsum[b];
    #pragma unroll
    for (int k = 0; k < 4; ++k) {
        int i = base + k;
        if (i < n) { rowptr[i] = run; cursor[i] = run; }
        run += v[k];
    }
    if (b == 0 && t == 0) rowptr[n] = e;
}

__global__ void fill_csr(const int* __restrict__ ei, int* __restrict__ cursor,
                         int* __restrict__ colarr, int e) {
    int i = blockIdx.x * 256 + threadIdx.x;
    if (i < e) {
        int d = ei[e + i];
        int pos = atomicAdd(&cursor[d], 1);
        colarr[pos] = ei[i];   // src
    }
}

// ---------------- aggregation ----------------

// d=7: h0[node][0..6] = x[node] + sum_{j->node} x[src_j]; h0 stride 8, pad col = 0
__global__ __launch_bounds__(256) void agg7(const float* __restrict__ xin,
        const int* __restrict__ rowptr, const int* __restrict__ colarr,
        float* __restrict__ h0, int n) {
    int node = blockIdx.x * 32 + (threadIdx.x >> 3);
    int f = threadIdx.x & 7;
    if (node >= n) return;
    int fidx = (f < 7) ? f : 0;
    float acc = xin[node * 7 + fidx];
    int beg = rowptr[node], end = rowptr[node + 1];
    int j = beg;
    for (; j + 4 <= end; j += 4) {
        int s0 = colarr[j], s1 = colarr[j+1], s2 = colarr[j+2], s3 = colarr[j+3];
        float v0 = xin[s0*7 + fidx], v1 = xin[s1*7 + fidx];
        float v2 = xin[s2*7 + fidx], v3 = xin[s3*7 + fidx];
        acc += (v0 + v1) + (v2 + v3);
    }
    for (; j < end; ++j) acc += xin[colarr[j]*7 + fidx];
    h0[node * 8 + f] = (f < 7) ? acc : 0.f;
}

// d=128: h[node][t] = x[node][t] + sum neighbors
__global__ __launch_bounds__(256) void agg128(const float* __restrict__ xin,
        const int* __restrict__ rowptr, const int* __restrict__ colarr,
        float* __restrict__ hout, int n) {
    int node = blockIdx.x * 2 + (threadIdx.x >> 7);
    int t = threadIdx.x & 127;
    if (node >= n) return;
    float acc = xin[node * 128 + t];
    int beg = rowptr[node], end = rowptr[node + 1];
    int j = beg;
    for (; j + 4 <= end; j += 4) {
        int s0 = colarr[j], s1 = colarr[j+1], s2 = colarr[j+2], s3 = colarr[j+3];
        float v0 = xin[s0*128 + t], v1 = xin[s1*128 + t];
        float v2 = xin[s2*128 + t], v3 = xin[s3*128 + t];
        acc += (v0 + v1) + (v2 + v3);
    }
    for (; j < end; ++j) acc += xin[colarr[j]*128 + t];
    hout[node * 128 + t] = acc;
}

// ---------------- GEMMs ----------------

// t0 = relu(h0 @ W0a + b0a), h0 stride 8 (col 7 zero), W0a [7][128]
__global__ __launch_bounds__(256) void lin7(const float* __restrict__ h0,
        const float* __restrict__ W, const float* __restrict__ bias,
        float* __restrict__ out, int n) {
    __shared__ float wl[7][128];
    __shared__ float hl[8][8];
    int t = threadIdx.x;
    for (int l = t; l < 7 * 128; l += 256) wl[l >> 7][l & 127] = W[l];  // FIX: full 896-elem staging
    int row0 = blockIdx.x * 8;
    if (t < 64) {
        int r = t >> 3, k = t & 7;
        int gr = row0 + r;
        hl[r][k] = (gr < n) ? h0[gr * 8 + k] : 0.f;
    }
    __syncthreads();
    int c = t & 127, g = t >> 7;
    float bv = bias[c];
    #pragma unroll
    for (int i = 0; i < 4; ++i) {
        int r = g * 4 + i, gr = row0 + r;
        if (gr < n) {
            float acc = bv;
            #pragma unroll
            for (int k = 0; k < 7; ++k) acc += hl[r][k] * wl[k][c];
            out[gr * 128 + c] = fmaxf(acc, 0.f);
        }
    }
}

// out[N,128] = relu(in[N,128] @ W[128,128] + b); 64 rows/block, 4x8 microtile
template<bool RELU>
__global__ __launch_bounds__(256) void lin128(const float* __restrict__ in,
        const float* __restrict__ W, const float* __restrict__ bias,
        float* __restrict__ out, int n) {
    __shared__ float w_lds[64][128];
    __shared__ float a_lds[64][65];
    int t = threadIdx.x;
    int tx = t & 15;      // col group: cols tx*8 .. tx*8+7
    int ty = t >> 4;      // row group: rows ty*4 .. ty*4+3
    int row0 = blockIdx.x * 64;
    float acc[4][8];
    #pragma unroll
    for (int i = 0; i < 4; ++i)
        #pragma unroll
        for (int j = 0; j < 8; ++j) acc[i][j] = 0.f;

    for (int kk = 0; kk < 128; kk += 64) {
        #pragma unroll
        for (int it = 0; it < 8; ++it) {          // W chunk: 2048 float4
            int l = t + 256 * it;
            int k = l >> 5, c4 = (l & 31) * 4;
            float4 wv = *(const float4*)&W[(kk + k) * 128 + c4];
            *(float4*)&w_lds[k][c4] = wv;
        }
        #pragma unroll
        for (int it = 0; it < 4; ++it) {          // A chunk: 1024 float4
            int l = t + 256 * it;
            int r = l >> 4, k4 = (l & 15) * 4;
            int gr = row0 + r;
            float4 av = make_float4(0.f, 0.f, 0.f, 0.f);
            if (gr < n) av = *(const float4*)&in[gr * 128 + kk + k4];
            a_lds[r][k4 + 0] = av.x; a_lds[r][k4 + 1] = av.y;
            a_lds[r][k4 + 2] = av.z; a_lds[r][k4 + 3] = av.w;
        }
        __syncthreads();
        #pragma unroll
        for (int k = 0; k < 64; ++k) {
            float4 w0 = *(const float4*)&w_lds[k][tx * 8];
            float4 w1 = *(const float4*)&w_lds[k][tx * 8 + 4];
            float b[8] = {w0.x, w0.y, w0.z, w0.w, w1.x, w1.y, w1.z, w1.w};
            float a0 = a_lds[ty * 4 + 0][k];
            float a1 = a_lds[ty * 4 + 1][k];
            float a2 = a_lds[ty * 4 + 2][k];
            float a3 = a_lds[ty * 4 + 3][k];
            #pragma unroll
            for (int j = 0; j < 8; ++j) {
                acc[0][j] += a0 * b[j];
                acc[1][j] += a1 * b[j];
                acc[2][j] += a2 * b[j];
                acc[3][j] += a3 * b[j];
            }
        }
        __syncthreads();
    }
    int c0 = tx * 8;
    float bv[8];
    #pragma unroll
    for (int j = 0; j < 8; ++j) bv[j] = bias[c0 + j];
    #pragma unroll
    for (int i = 0; i < 4; ++i) {
        int gr = row0 + ty * 4 + i;
        if (gr < n) {
            float o[8];
            #pragma unroll
            for (int j = 0; j < 8; ++j) {
                float v = acc[i][j] + bv[j];
                o[j] = RELU ? fmaxf(v, 0.f) : v;
            }
            *(float4*)&out[gr * 128 + c0]     = make_float4(o[0], o[1], o[2], o[3]);
            *(float4*)&out[gr * 128 + c0 + 4] = make_float4(o[4], o[5], o[6], o[7]);
        }
    }
}

// pooled[batch[r]] += in[r] @ W[128,128] (+ bias per node if ADDB)
template<bool ADDB>
__global__ __launch_bounds__(256) void jk_pool(const float* __restrict__ in,
        const float* __restrict__ W, const float* __restrict__ bias,
        const int* __restrict__ batch, float* __restrict__ pooled, int n) {
    __shared__ float w_lds[64][128];
    __shared__ float a_lds[64][65];
    int t = threadIdx.x;
    int tx = t & 15;
    int ty = t >> 4;
    int row0 = blockIdx.x * 64;
    float acc[4][8];
    #pragma unroll
    for (int i = 0; i < 4; ++i)
        #pragma unroll
        for (int j = 0; j < 8; ++j) acc[i][j] = 0.f;

    for (int kk = 0; kk < 128; kk += 64) {
        #pragma unroll
        for (int it = 0; it < 8; ++it) {
            int l = t + 256 * it;
            int k = l >> 5, c4 = (l & 31) * 4;
            float4 wv = *(const float4*)&W[(kk + k) * 128 + c4];
            *(float4*)&w_lds[k][c4] = wv;
        }
        #pragma unroll
        for (int it = 0; it < 4; ++it) {
            int l = t + 256 * it;
            int r = l >> 4, k4 = (l & 15) * 4;
            int gr = row0 + r;
            float4 av = make_float4(0.f, 0.f, 0.f, 0.f);
            if (gr < n) av = *(const float4*)&in[gr * 128 + kk + k4];
            a_lds[r][k4 + 0] = av.x; a_lds[r][k4 + 1] = av.y;
            a_lds[r][k4 + 2] = av.z; a_lds[r][k4 + 3] = av.w;
        }
        __syncthreads();
        #pragma unroll
        for (int k = 0; k < 64; ++k) {
            float4 w0 = *(const float4*)&w_lds[k][tx * 8];
            float4 w1 = *(const float4*)&w_lds[k][tx * 8 + 4];
            float b[8] = {w0.x, w0.y, w0.z, w0.w, w1.x, w1.y, w1.z, w1.w};
            float a0 = a_lds[ty * 4 + 0][k];
            float a1 = a_lds[ty * 4 + 1][k];
            float a2 = a_lds[ty * 4 + 2][k];
            float a3 = a_lds[ty * 4 + 3][k];
            #pragma unroll
            for (int j = 0; j < 8; ++j) {
                acc[0][j] += a0 * b[j];
                acc[1][j] += a1 * b[j];
                acc[2][j] += a2 * b[j];
                acc[3][j] += a3 * b[j];
            }
        }
        __syncthreads();
    }
    int c0 = tx * 8;
    if (ADDB) {
        float bv[8];
        #pragma unroll
        for (int j = 0; j < 8; ++j) bv[j] = bias[c0 + j];
        #pragma unroll
        for (int i = 0; i < 4; ++i) {
            int gr = row0 + ty * 4 + i;
            if (gr < n) {
                #pragma unroll
                for (int j = 0; j < 8; ++j) acc[i][j] += bv[j];
            }
        }
    }
    int row_last = row0 + 63; if (row_last > n - 1) row_last = n - 1;
    int g_first = batch[row0];
    int g_last  = batch[row_last];
    if (g_first == g_last) {
        // whole block in one graph: LDS reduce, 128 atomics
        float s[8];
        #pragma unroll
        for (int j = 0; j < 8; ++j)
            s[j] = (acc[0][j] + acc[1][j]) + (acc[2][j] + acc[3][j]);
        float* red = &a_lds[0][0];   // reuse (>=2048 floats)
        #pragma unroll
        for (int j = 0; j < 8; ++j) red[ty * 128 + c0 + j] = s[j];
        __syncthreads();
        if (t < 128) {
            float tot = 0.f;
            #pragma unroll
            for (int g = 0; g < 16; ++g) tot += red[g * 128 + t];
            atomicAdd(&pooled[g_first * 128 + t], tot);
        }
    } else {
        #pragma unroll
        for (int i = 0; i < 4; ++i) {
            int gr = row0 + ty * 4 + i;
            if (gr < n) {
                int g = batch[gr];
                #pragma unroll
                for (int j = 0; j < 8; ++j)
                    atomicAdd(&pooled[g * 128 + c0 + j], acc[i][j]);
            }
        }
    }
}

// ---------------- classifier ----------------

__global__ __launch_bounds__(256) void classifier(const float* __restrict__ pooled,
        const float* __restrict__ Wc1, const float* __restrict__ bc1,
        const float* __restrict__ gamma, const float* __restrict__ beta,
        const float* __restrict__ rmean, const float* __restrict__ rvar,
        const float* __restrict__ Wc2, const float* __restrict__ bc2,
        float* __restrict__ out) {
    int g = blockIdx.x, t = threadIdx.x;
    __shared__ float p[128];
    __shared__ float r0[256], r1[256];
    if (t < 128) p[t] = pooled[g * 128 + t];
    __syncthreads();
    float acc = bc1[t];
    #pragma unroll 8
    for (int k = 0; k < 128; ++k) acc += p[k] * Wc1[k * 256 + t];
    float z = (acc - rmean[t]) * rsqrtf(rvar[t] + 1e-5f) * gamma[t] + beta[t];
    z = fmaxf(z, 0.f);
    r0[t] = z * Wc2[t * 2 + 0];
    r1[t] = z * Wc2[t * 2 + 1];
    __syncthreads();
    for (int s = 128; s > 0; s >>= 1) {
        if (t < s) { r0[t] += r0[t + s]; r1[t] += r1[t + s]; }
        __syncthreads();
    }
    if (t == 0) {
        out[g * 2 + 0] = r0[0] + bc2[0];
        out[g * 2 + 1] = r1[0] + bc2[1];
    }
}

// ---------------- launch ----------------

static inline size_t al256(size_t x) { return (x + 255) & ~size_t(255); }

extern "C" void kernel_launch(void* const* d_in, const int* in_sizes, int n_in,
                              void* d_out, int out_size, void* d_ws, size_t ws_size,
                              hipStream_t stream) {
    const float* x    = (const float*)d_in[0];
    const int*   ei   = (const int*)  d_in[1];
    const int*   batch= (const int*)  d_in[3];
    const float* W0a = (const float*)d_in[4];  const float* b0a = (const float*)d_in[5];
    const float* W0b = (const float*)d_in[6];  const float* b0b = (const float*)d_in[7];
    const float* W1a = (const float*)d_in[8];  const float* b1a = (const float*)d_in[9];
    const float* W1b = (const float*)d_in[10]; const float* b1b = (const float*)d_in[11];
    const float* W2a = (const float*)d_in[12]; const float* b2a = (const float*)d_in[13];
    const float* W2b = (const float*)d_in[14]; const float* b2b = (const float*)d_in[15];
    const float* Wjk = (const float*)d_in[16]; const float* bjk = (const float*)d_in[17];
    const float* Wc1 = (const float*)d_in[18]; const float* bc1 = (const float*)d_in[19];
    const float* gamma=(const float*)d_in[20]; const float* beta= (const float*)d_in[21];
    const float* rmean=(const float*)d_in[22]; const float* rvar= (const float*)d_in[23];
    const float* Wc2 = (const float*)d_in[24]; const float* bc2 = (const float*)d_in[25];
    float* out = (float*)d_out;

    const int N = NN, E = EE, B = BB;

    char* w = (char*)d_ws;
    size_t off = 0;
    int* deg    = (int*)(w + off); off = al256(off + (size_t)N * 4);
    int* rowptr = (int*)(w + off); off = al256(off + (size_t)(N + 1) * 4);
    int* cursor = (int*)(w + off); off = al256(off + (size_t)N * 4);
    int* colarr = (int*)(w + off); off = al256(off + (size_t)E * 4);
    int* bsum   = (int*)(w + off); off = al256(off + 1024 * 4);
    float* h0   = (float*)(w + off); off = al256(off + (size_t)N * 8 * 4);
    float* SA   = (float*)(w + off); off = al256(off + (size_t)N * 128 * 4);
    float* SB   = (float*)(w + off); off = al256(off + (size_t)N * 128 * 4);
    float* XC   = (float*)(w + off); off = al256(off + (size_t)N * 128 * 4);
    float* pooled = (float*)(w + off); off = al256(off + (size_t)B * 128 * 4);

    hipMemsetAsync(deg, 0, (size_t)N * 4, stream);
    hipMemsetAsync(pooled, 0, (size_t)B * 128 * 4, stream);

    int nb = (N + 1023) / 1024;   // 98

    count_deg<<<(E + 255) / 256, 256, 0, stream>>>(ei, deg, E);
    scan_partial<<<nb, 256, 0, stream>>>(deg, bsum, N);
    scan_bsum<<<1, 256, 0, stream>>>(bsum, nb);
    scan_apply<<<nb, 256, 0, stream>>>(deg, bsum, rowptr, cursor, N, E);
    fill_csr<<<(E + 255) / 256, 256, 0, stream>>>(ei, cursor, colarr, E);

    int gLin = (N + 63) / 64;

    // Layer 0
    agg7<<<(N + 31) / 32, 256, 0, stream>>>(x, rowptr, colarr, h0, N);
    lin7<<<(N + 7) / 8, 256, 0, stream>>>(h0, W0a, b0a, SB, N);
    lin128<true><<<gLin, 256, 0, stream>>>(SB, W0b, b0b, XC, N);            // x1
    jk_pool<false><<<gLin, 256, 0, stream>>>(XC, Wjk, bjk, batch, pooled, N);

    // Layer 1
    agg128<<<(N + 1) / 2, 256, 0, stream>>>(XC, rowptr, colarr, SA, N);
    lin128<true><<<gLin, 256, 0, stream>>>(SA, W1a, b1a, SB, N);
    lin128<true><<<gLin, 256, 0, stream>>>(SB, W1b, b1b, XC, N);            // x2
    jk_pool<false><<<gLin, 256, 0, stream>>>(XC, Wjk + 128 * 128, bjk, batch, pooled, N);

    // Layer 2
    agg128<<<(N + 1) / 2, 256, 0, stream>>>(XC, rowptr, colarr, SA, N);
    lin128<true><<<gLin, 256, 0, stream>>>(SA, W2a, b2a, SB, N);
    lin128<true><<<gLin, 256, 0, stream>>>(SB, W2b, b2b, XC, N);            // x3
    jk_pool<true><<<gLin, 256, 0, stream>>>(XC, Wjk + 256 * 128, bjk, batch, pooled, N);

    classifier<<<B, 256, 0, stream>>>(pooled, Wc1, bc1, gamma, beta,
                                      rmean, rvar, Wc2, bc2, out);
}

// Round 3
// 1319.316 us; speedup vs baseline: 1.0164x; 1.0164x over previous
//
#include <hip/hip_runtime.h>

#define NN 100000
#define EE 1600000
#define BB 256
#define IN_F 7
#define HH 128

// ---------------- CSR build ----------------

__global__ void count_deg(const int* __restrict__ ei, int* __restrict__ deg, int e) {
    int i = blockIdx.x * 256 + threadIdx.x;
    if (i < e) atomicAdd(&deg[ei[e + i]], 1);   // dst = ei[E + i]
}

__global__ void scan_partial(const int* __restrict__ deg, int* __restrict__ bsum, int n) {
    __shared__ int sd[256];
    int b = blockIdx.x, t = threadIdx.x;
    int base = b * 1024 + t * 4;
    int s = 0;
    #pragma unroll
    for (int k = 0; k < 4; ++k) { int i = base + k; if (i < n) s += deg[i]; }
    sd[t] = s; __syncthreads();
    for (int off = 128; off > 0; off >>= 1) {
        if (t < off) sd[t] += sd[t + off];
        __syncthreads();
    }
    if (t == 0) bsum[b] = sd[0];
}

__global__ void scan_bsum(int* __restrict__ bsum, int nb) {
    __shared__ int sd[256];
    int t = threadIdx.x;
    int v = (t < nb) ? bsum[t] : 0;
    sd[t] = v; __syncthreads();
    for (int off = 1; off < 256; off <<= 1) {
        int add = (t >= off) ? sd[t - off] : 0;
        __syncthreads();
        sd[t] += add;
        __syncthreads();
    }
    if (t < nb) bsum[t] = sd[t] - v;   // exclusive
}

__global__ void scan_apply(const int* __restrict__ deg, const int* __restrict__ bsum,
                           int* __restrict__ rowptr, int* __restrict__ cursor, int n, int e) {
    __shared__ int sd[256];
    int b = blockIdx.x, t = threadIdx.x;
    int base = b * 1024 + t * 4;
    int v[4]; int s = 0;
    #pragma unroll
    for (int k = 0; k < 4; ++k) { int i = base + k; v[k] = (i < n) ? deg[i] : 0; s += v[k]; }
    sd[t] = s; __syncthreads();
    int mine = s;
    for (int off = 1; off < 256; off <<= 1) {
        int add = (t >= off) ? sd[t - off] : 0;
        __syncthreads();
        sd[t] += add;
        __syncthreads();
    }
    int run = sd[t] - mine + bsum[b];
    #pragma unroll
    for (int k = 0; k < 4; ++k) {
        int i = base + k;
        if (i < n) { rowptr[i] = run; cursor[i] = run; }
        run += v[k];
    }
    if (b == 0 && t == 0) rowptr[n] = e;
}

__global__ void fill_csr(const int* __restrict__ ei, int* __restrict__ cursor,
                         int* __restrict__ colarr, int e) {
    int i = blockIdx.x * 256 + threadIdx.x;
    if (i < e) {
        int d = ei[e + i];
        int pos = atomicAdd(&cursor[d], 1);
        colarr[pos] = ei[i];   // src
    }
}

// ---------------- aggregation ----------------

// d=7: h0[node][0..6] = x[node] + sum_{j->node} x[src_j]; h0 stride 8, pad col = 0
__global__ __launch_bounds__(256) void agg7(const float* __restrict__ xin,
        const int* __restrict__ rowptr, const int* __restrict__ colarr,
        float* __restrict__ h0, int n) {
    int node = blockIdx.x * 32 + (threadIdx.x >> 3);
    int f = threadIdx.x & 7;
    if (node >= n) return;
    int fidx = (f < 7) ? f : 0;
    float acc = xin[node * 7 + fidx];
    int beg = rowptr[node], end = rowptr[node + 1];
    int j = beg;
    for (; j + 4 <= end; j += 4) {
        int s0 = colarr[j], s1 = colarr[j+1], s2 = colarr[j+2], s3 = colarr[j+3];
        float v0 = xin[s0*7 + fidx], v1 = xin[s1*7 + fidx];
        float v2 = xin[s2*7 + fidx], v3 = xin[s3*7 + fidx];
        acc += (v0 + v1) + (v2 + v3);
    }
    for (; j < end; ++j) acc += xin[colarr[j]*7 + fidx];
    h0[node * 8 + f] = (f < 7) ? acc : 0.f;
}

// d=128: h[node][t] = x[node][t] + sum neighbors
__global__ __launch_bounds__(256) void agg128(const float* __restrict__ xin,
        const int* __restrict__ rowptr, const int* __restrict__ colarr,
        float* __restrict__ hout, int n) {
    int node = blockIdx.x * 2 + (threadIdx.x >> 7);
    int t = threadIdx.x & 127;
    if (node >= n) return;
    float acc = xin[node * 128 + t];
    int beg = rowptr[node], end = rowptr[node + 1];
    int j = beg;
    for (; j + 4 <= end; j += 4) {
        int s0 = colarr[j], s1 = colarr[j+1], s2 = colarr[j+2], s3 = colarr[j+3];
        float v0 = xin[s0*128 + t], v1 = xin[s1*128 + t];
        float v2 = xin[s2*128 + t], v3 = xin[s3*128 + t];
        acc += (v0 + v1) + (v2 + v3);
    }
    for (; j < end; ++j) acc += xin[colarr[j]*128 + t];
    hout[node * 128 + t] = acc;
}

// ---------------- small first linear ----------------

// t0 = relu(h0 @ W0a + b0a), h0 stride 8 (col 7 zero), W0a [7][128]
__global__ __launch_bounds__(256) void lin7(const float* __restrict__ h0,
        const float* __restrict__ W, const float* __restrict__ bias,
        float* __restrict__ out, int n) {
    __shared__ float wl[7][128];
    __shared__ float hl[8][8];
    int t = threadIdx.x;
    for (int l = t; l < 7 * 128; l += 256) wl[l >> 7][l & 127] = W[l];
    int row0 = blockIdx.x * 8;
    if (t < 64) {
        int r = t >> 3, k = t & 7;
        int gr = row0 + r;
        hl[r][k] = (gr < n) ? h0[gr * 8 + k] : 0.f;
    }
    __syncthreads();
    int c = t & 127, g = t >> 7;
    float bv = bias[c];
    #pragma unroll
    for (int i = 0; i < 4; ++i) {
        int r = g * 4 + i, gr = row0 + r;
        if (gr < n) {
            float acc = bv;
            #pragma unroll
            for (int k = 0; k < 7; ++k) acc += hl[r][k] * wl[k][c];
            out[gr * 128 + c] = fmaxf(acc, 0.f);
        }
    }
}

// ---------------- fused MLP + JK + pool ----------------

// GEMM core: acc[4][8] = a_lds(64x128) @ W(128x128), W staged in 32-row chunks.
// Caller must __syncthreads() after return before touching w_lds/a_lds.
__device__ __forceinline__ void gemm_core(const float* __restrict__ W,
        float (&w_lds)[32][128], float (&a_lds)[64][132],
        int t, int tx, int ty, float (&acc)[4][8])
{
    #pragma unroll
    for (int i = 0; i < 4; ++i)
        #pragma unroll
        for (int j = 0; j < 8; ++j) acc[i][j] = 0.f;
    for (int kk = 0; kk < 128; kk += 32) {
        __syncthreads();   // previous chunk consumers done / a_lds writes visible
        #pragma unroll
        for (int it = 0; it < 4; ++it) {     // 32x128 floats = 1024 float4
            int l = t + 256 * it;
            int k = l >> 5, c4 = (l & 31) * 4;
            *(float4*)&w_lds[k][c4] = *(const float4*)&W[(kk + k) * 128 + c4];
        }
        __syncthreads();
        #pragma unroll
        for (int k = 0; k < 32; ++k) {
            float4 w0 = *(const float4*)&w_lds[k][tx * 8];
            float4 w1 = *(const float4*)&w_lds[k][tx * 8 + 4];
            float bw[8] = {w0.x, w0.y, w0.z, w0.w, w1.x, w1.y, w1.z, w1.w};
            float a0 = a_lds[ty * 4 + 0][kk + k];
            float a1 = a_lds[ty * 4 + 1][kk + k];
            float a2 = a_lds[ty * 4 + 2][kk + k];
            float a3 = a_lds[ty * 4 + 3][kk + k];
            #pragma unroll
            for (int j = 0; j < 8; ++j) {
                acc[0][j] += a0 * bw[j];
                acc[1][j] += a1 * bw[j];
                acc[2][j] += a2 * bw[j];
                acc[3][j] += a3 * bw[j];
            }
        }
    }
}

// Per layer: [t = relu(in@Wa+ba)] ; x = relu(t@Wb+bb) ; y = x@Wjk(+bjk) ; pooled += y
// DO_A=false: `in` is already t (layer 0: lin7 output).
// WRITE_X: store x for the next layer's aggregation (not needed for layer 2).
template<bool DO_A, bool LASTB, bool WRITE_X>
__global__ __launch_bounds__(256) void mlp_fused(
        const float* __restrict__ in,
        const float* __restrict__ Wa, const float* __restrict__ ba,
        const float* __restrict__ Wb, const float* __restrict__ bb,
        const float* __restrict__ Wjk, const float* __restrict__ bjk,
        const int* __restrict__ batch,
        float* __restrict__ xout, float* __restrict__ pooled, int n)
{
    __shared__ float w_lds[32][128];   // 16 KB (also pooling scratch: 4096 floats)
    __shared__ float a_lds[64][132];   // 33 KB
    int t = threadIdx.x, tx = t & 15, ty = t >> 4;
    int row0 = blockIdx.x * 64;
    int c0 = tx * 8;
    float acc[4][8];

    // stage input rows (zero-fill invalid rows)
    #pragma unroll
    for (int it = 0; it < 8; ++it) {
        int l = t + 256 * it;
        int r = l >> 5, c4 = (l & 31) * 4;
        int gr = row0 + r;
        float4 av = make_float4(0.f, 0.f, 0.f, 0.f);
        if (gr < n) av = *(const float4*)&in[gr * 128 + c4];
        *(float4*)&a_lds[r][c4] = av;
    }
    // (gemm_core's entry barrier makes these writes visible)

    if (DO_A) {
        gemm_core(Wa, w_lds, a_lds, t, tx, ty, acc);
        __syncthreads();
        float bv[8];
        #pragma unroll
        for (int j = 0; j < 8; ++j) bv[j] = ba[c0 + j];
        #pragma unroll
        for (int i = 0; i < 4; ++i) {
            int r = ty * 4 + i, gr = row0 + r;
            #pragma unroll
            for (int j = 0; j < 8; ++j)
                a_lds[r][c0 + j] = (gr < n) ? fmaxf(acc[i][j] + bv[j], 0.f) : 0.f;
        }
    }

    gemm_core(Wb, w_lds, a_lds, t, tx, ty, acc);
    __syncthreads();
    {
        float bv[8];
        #pragma unroll
        for (int j = 0; j < 8; ++j) bv[j] = bb[c0 + j];
        #pragma unroll
        for (int i = 0; i < 4; ++i) {
            int r = ty * 4 + i, gr = row0 + r;
            float o[8];
            #pragma unroll
            for (int j = 0; j < 8; ++j)
                o[j] = (gr < n) ? fmaxf(acc[i][j] + bv[j], 0.f) : 0.f;
            #pragma unroll
            for (int j = 0; j < 8; ++j) a_lds[r][c0 + j] = o[j];
            if (WRITE_X && gr < n) {
                *(float4*)&xout[gr * 128 + c0]     = make_float4(o[0], o[1], o[2], o[3]);
                *(float4*)&xout[gr * 128 + c0 + 4] = make_float4(o[4], o[5], o[6], o[7]);
            }
        }
    }

    gemm_core(Wjk, w_lds, a_lds, t, tx, ty, acc);
    __syncthreads();

    if (LASTB) {
        float bv[8];
        #pragma unroll
        for (int j = 0; j < 8; ++j) bv[j] = bjk[c0 + j];
        #pragma unroll
        for (int i = 0; i < 4; ++i) {
            int gr = row0 + ty * 4 + i;
            if (gr < n) {
                #pragma unroll
                for (int j = 0; j < 8; ++j) acc[i][j] += bv[j];
            }
        }
    }

    int row_last = row0 + 63; if (row_last > n - 1) row_last = n - 1;
    int g_first = batch[row0];
    int g_last  = batch[row_last];
    float* red = &w_lds[0][0];   // 4096 floats scratch
    if (g_first == g_last) {
        float s[8];
        #pragma unroll
        for (int j = 0; j < 8; ++j)
            s[j] = (acc[0][j] + acc[1][j]) + (acc[2][j] + acc[3][j]);
        #pragma unroll
        for (int j = 0; j < 8; ++j) red[ty * 128 + c0 + j] = s[j];
        __syncthreads();
        if (t < 128) {
            float tot = 0.f;
            #pragma unroll
            for (int g = 0; g < 16; ++g) tot += red[g * 128 + t];
            atomicAdd(&pooled[g_first * 128 + t], tot);
        }
    } else {
        #pragma unroll
        for (int i = 0; i < 4; ++i) {
            int gr = row0 + ty * 4 + i;
            if (gr < n) {
                int g = batch[gr];
                #pragma unroll
                for (int j = 0; j < 8; ++j)
                    atomicAdd(&pooled[g * 128 + c0 + j], acc[i][j]);
            }
        }
    }
}

// ---------------- classifier ----------------

__global__ __launch_bounds__(256) void classifier(const float* __restrict__ pooled,
        const float* __restrict__ Wc1, const float* __restrict__ bc1,
        const float* __restrict__ gamma, const float* __restrict__ beta,
        const float* __restrict__ rmean, const float* __restrict__ rvar,
        const float* __restrict__ Wc2, const float* __restrict__ bc2,
        float* __restrict__ out) {
    int g = blockIdx.x, t = threadIdx.x;
    __shared__ float p[128];
    __shared__ float r0[256], r1[256];
    if (t < 128) p[t] = pooled[g * 128 + t];
    __syncthreads();
    float acc = bc1[t];
    #pragma unroll 8
    for (int k = 0; k < 128; ++k) acc += p[k] * Wc1[k * 256 + t];
    float z = (acc - rmean[t]) * rsqrtf(rvar[t] + 1e-5f) * gamma[t] + beta[t];
    z = fmaxf(z, 0.f);
    r0[t] = z * Wc2[t * 2 + 0];
    r1[t] = z * Wc2[t * 2 + 1];
    __syncthreads();
    for (int s = 128; s > 0; s >>= 1) {
        if (t < s) { r0[t] += r0[t + s]; r1[t] += r1[t + s]; }
        __syncthreads();
    }
    if (t == 0) {
        out[g * 2 + 0] = r0[0] + bc2[0];
        out[g * 2 + 1] = r1[0] + bc2[1];
    }
}

// ---------------- launch ----------------

static inline size_t al256(size_t x) { return (x + 255) & ~size_t(255); }

extern "C" void kernel_launch(void* const* d_in, const int* in_sizes, int n_in,
                              void* d_out, int out_size, void* d_ws, size_t ws_size,
                              hipStream_t stream) {
    const float* x    = (const float*)d_in[0];
    const int*   ei   = (const int*)  d_in[1];
    const int*   batch= (const int*)  d_in[3];
    const float* W0a = (const float*)d_in[4];  const float* b0a = (const float*)d_in[5];
    const float* W0b = (const float*)d_in[6];  const float* b0b = (const float*)d_in[7];
    const float* W1a = (const float*)d_in[8];  const float* b1a = (const float*)d_in[9];
    const float* W1b = (const float*)d_in[10]; const float* b1b = (const float*)d_in[11];
    const float* W2a = (const float*)d_in[12]; const float* b2a = (const float*)d_in[13];
    const float* W2b = (const float*)d_in[14]; const float* b2b = (const float*)d_in[15];
    const float* Wjk = (const float*)d_in[16]; const float* bjk = (const float*)d_in[17];
    const float* Wc1 = (const float*)d_in[18]; const float* bc1 = (const float*)d_in[19];
    const float* gamma=(const float*)d_in[20]; const float* beta= (const float*)d_in[21];
    const float* rmean=(const float*)d_in[22]; const float* rvar= (const float*)d_in[23];
    const float* Wc2 = (const float*)d_in[24]; const float* bc2 = (const float*)d_in[25];
    float* out = (float*)d_out;

    const int N = NN, E = EE, B = BB;

    char* w = (char*)d_ws;
    size_t off = 0;
    int* deg    = (int*)(w + off); off = al256(off + (size_t)N * 4);
    int* rowptr = (int*)(w + off); off = al256(off + (size_t)(N + 1) * 4);
    int* cursor = (int*)(w + off); off = al256(off + (size_t)N * 4);
    int* colarr = (int*)(w + off); off = al256(off + (size_t)E * 4);
    int* bsum   = (int*)(w + off); off = al256(off + 1024 * 4);
    float* h0   = (float*)(w + off); off = al256(off + (size_t)N * 8 * 4);
    float* SA   = (float*)(w + off); off = al256(off + (size_t)N * 128 * 4);
    float* SB   = (float*)(w + off); off = al256(off + (size_t)N * 128 * 4);
    float* XC   = (float*)(w + off); off = al256(off + (size_t)N * 128 * 4);
    float* pooled = (float*)(w + off); off = al256(off + (size_t)B * 128 * 4);

    hipMemsetAsync(deg, 0, (size_t)N * 4, stream);
    hipMemsetAsync(pooled, 0, (size_t)B * 128 * 4, stream);

    int nb = (N + 1023) / 1024;   // 98

    count_deg<<<(E + 255) / 256, 256, 0, stream>>>(ei, deg, E);
    scan_partial<<<nb, 256, 0, stream>>>(deg, bsum, N);
    scan_bsum<<<1, 256, 0, stream>>>(bsum, nb);
    scan_apply<<<nb, 256, 0, stream>>>(deg, bsum, rowptr, cursor, N, E);
    fill_csr<<<(E + 255) / 256, 256, 0, stream>>>(ei, cursor, colarr, E);

    int gLin = (N + 63) / 64;

    // Layer 0: agg(d=7) -> lin7 (= t0) -> fused [x1=relu(t0@W0b+b0b); jk0; pool]
    agg7<<<(N + 31) / 32, 256, 0, stream>>>(x, rowptr, colarr, h0, N);
    lin7<<<(N + 7) / 8, 256, 0, stream>>>(h0, W0a, b0a, SB, N);
    mlp_fused<false, false, true><<<gLin, 256, 0, stream>>>(
        SB, nullptr, nullptr, W0b, b0b, Wjk, nullptr, batch, XC, pooled, N);

    // Layer 1
    agg128<<<(N + 1) / 2, 256, 0, stream>>>(XC, rowptr, colarr, SA, N);
    mlp_fused<true, false, true><<<gLin, 256, 0, stream>>>(
        SA, W1a, b1a, W1b, b1b, Wjk + 128 * 128, nullptr, batch, XC, pooled, N);

    // Layer 2 (x3 never materialized)
    agg128<<<(N + 1) / 2, 256, 0, stream>>>(XC, rowptr, colarr, SA, N);
    mlp_fused<true, true, false><<<gLin, 256, 0, stream>>>(
        SA, W2a, b2a, W2b, b2b, Wjk + 256 * 128, bjk, batch, nullptr, pooled, N);

    classifier<<<B, 256, 0, stream>>>(pooled, Wc1, bc1, gamma, beta,
                                      rmean, rvar, Wc2, bc2, out);
}

// Round 4
// 1209.057 us; speedup vs baseline: 1.1091x; 1.0912x over previous
//
#include <hip/hip_runtime.h>

#define NN 100000
#define EE 1600000
#define BB 256
#define IN_F 7
#define HH 128

// ---------------- CSR build ----------------

__global__ void count_deg(const int* __restrict__ ei, int* __restrict__ deg, int e) {
    int i = blockIdx.x * 256 + threadIdx.x;
    if (i < e) atomicAdd(&deg[ei[e + i]], 1);   // dst = ei[E + i]
}

__global__ void scan_partial(const int* __restrict__ deg, int* __restrict__ bsum, int n) {
    __shared__ int sd[256];
    int b = blockIdx.x, t = threadIdx.x;
    int base = b * 1024 + t * 4;
    int s = 0;
    #pragma unroll
    for (int k = 0; k < 4; ++k) { int i = base + k; if (i < n) s += deg[i]; }
    sd[t] = s; __syncthreads();
    for (int off = 128; off > 0; off >>= 1) {
        if (t < off) sd[t] += sd[t + off];
        __syncthreads();
    }
    if (t == 0) bsum[b] = sd[0];
}

__global__ void scan_bsum(int* __restrict__ bsum, int nb) {
    __shared__ int sd[256];
    int t = threadIdx.x;
    int v = (t < nb) ? bsum[t] : 0;
    sd[t] = v; __syncthreads();
    for (int off = 1; off < 256; off <<= 1) {
        int add = (t >= off) ? sd[t - off] : 0;
        __syncthreads();
        sd[t] += add;
        __syncthreads();
    }
    if (t < nb) bsum[t] = sd[t] - v;   // exclusive
}

__global__ void scan_apply(const int* __restrict__ deg, const int* __restrict__ bsum,
                           int* __restrict__ rowptr, int* __restrict__ cursor, int n, int e) {
    __shared__ int sd[256];
    int b = blockIdx.x, t = threadIdx.x;
    int base = b * 1024 + t * 4;
    int v[4]; int s = 0;
    #pragma unroll
    for (int k = 0; k < 4; ++k) { int i = base + k; v[k] = (i < n) ? deg[i] : 0; s += v[k]; }
    sd[t] = s; __syncthreads();
    int mine = s;
    for (int off = 1; off < 256; off <<= 1) {
        int add = (t >= off) ? sd[t - off] : 0;
        __syncthreads();
        sd[t] += add;
        __syncthreads();
    }
    int run = sd[t] - mine + bsum[b];
    #pragma unroll
    for (int k = 0; k < 4; ++k) {
        int i = base + k;
        if (i < n) { rowptr[i] = run; cursor[i] = run; }
        run += v[k];
    }
    if (b == 0 && t == 0) rowptr[n] = e;
}

__global__ void fill_csr(const int* __restrict__ ei, int* __restrict__ cursor,
                         int* __restrict__ colarr, int e) {
    int i = blockIdx.x * 256 + threadIdx.x;
    if (i < e) {
        int d = ei[e + i];
        int pos = atomicAdd(&cursor[d], 1);
        colarr[pos] = ei[i];   // src
    }
}

// ---------------- aggregation ----------------

__global__ __launch_bounds__(256) void agg7(const float* __restrict__ xin,
        const int* __restrict__ rowptr, const int* __restrict__ colarr,
        float* __restrict__ h0, int n) {
    int node = blockIdx.x * 32 + (threadIdx.x >> 3);
    int f = threadIdx.x & 7;
    if (node >= n) return;
    int fidx = (f < 7) ? f : 0;
    float acc = xin[node * 7 + fidx];
    int beg = rowptr[node], end = rowptr[node + 1];
    int j = beg;
    for (; j + 4 <= end; j += 4) {
        int s0 = colarr[j], s1 = colarr[j+1], s2 = colarr[j+2], s3 = colarr[j+3];
        float v0 = xin[s0*7 + fidx], v1 = xin[s1*7 + fidx];
        float v2 = xin[s2*7 + fidx], v3 = xin[s3*7 + fidx];
        acc += (v0 + v1) + (v2 + v3);
    }
    for (; j < end; ++j) acc += xin[colarr[j]*7 + fidx];
    h0[node * 8 + f] = (f < 7) ? acc : 0.f;
}

__global__ __launch_bounds__(256) void agg128(const float* __restrict__ xin,
        const int* __restrict__ rowptr, const int* __restrict__ colarr,
        float* __restrict__ hout, int n) {
    int node = blockIdx.x * 2 + (threadIdx.x >> 7);
    int t = threadIdx.x & 127;
    if (node >= n) return;
    float acc = xin[node * 128 + t];
    int beg = rowptr[node], end = rowptr[node + 1];
    int j = beg;
    for (; j + 4 <= end; j += 4) {
        int s0 = colarr[j], s1 = colarr[j+1], s2 = colarr[j+2], s3 = colarr[j+3];
        float v0 = xin[s0*128 + t], v1 = xin[s1*128 + t];
        float v2 = xin[s2*128 + t], v3 = xin[s3*128 + t];
        acc += (v0 + v1) + (v2 + v3);
    }
    for (; j < end; ++j) acc += xin[colarr[j]*128 + t];
    hout[node * 128 + t] = acc;
}

// ---------------- small first linear ----------------

__global__ __launch_bounds__(256) void lin7(const float* __restrict__ h0,
        const float* __restrict__ W, const float* __restrict__ bias,
        float* __restrict__ out, int n) {
    __shared__ float wl[7][128];
    __shared__ float hl[8][8];
    int t = threadIdx.x;
    for (int l = t; l < 7 * 128; l += 256) wl[l >> 7][l & 127] = W[l];
    int row0 = blockIdx.x * 8;
    if (t < 64) {
        int r = t >> 3, k = t & 7;
        int gr = row0 + r;
        hl[r][k] = (gr < n) ? h0[gr * 8 + k] : 0.f;
    }
    __syncthreads();
    int c = t & 127, g = t >> 7;
    float bv = bias[c];
    #pragma unroll
    for (int i = 0; i < 4; ++i) {
        int r = g * 4 + i, gr = row0 + r;
        if (gr < n) {
            float acc = bv;
            #pragma unroll
            for (int k = 0; k < 7; ++k) acc += hl[r][k] * wl[k][c];
            out[gr * 128 + c] = fmaxf(acc, 0.f);
        }
    }
}

// ---------------- fused MLP + JK + pool (128 threads, 8x8 microtile) ----------------

// XOR swizzle: logical col c of row r lives at physical col c ^ swz(r).
// swz spreads the ty-strided broadcast reads across bank quads (stride 8*132 == 0 mod 32).
__device__ __forceinline__ int swz(int r) { return ((r >> 2) & 7) * 4; }

// acc[8][8] = a_lds(64x128, swizzled) @ W(128x128, read from global/L1).
// Thread (tx,ty): rows ty*8..+7, cols tx*8..+7. No barriers inside.
__device__ __forceinline__ void gemm_core_g(const float* __restrict__ W,
        const float (&a_lds)[64][132], int tx, int ty, float (&acc)[8][8])
{
    #pragma unroll
    for (int i = 0; i < 8; ++i)
        #pragma unroll
        for (int j = 0; j < 8; ++j) acc[i][j] = 0.f;
    const float* Wp = W + tx * 8;
    const int r0 = ty * 8;
    for (int kk = 0; kk < 128; kk += 4) {
        float4 af[8];
        #pragma unroll
        for (int i = 0; i < 8; ++i)
            af[i] = *(const float4*)&a_lds[r0 + i][kk ^ swz(r0 + i)];
        #pragma unroll
        for (int dk = 0; dk < 4; ++dk) {
            float4 w0 = *(const float4*)&Wp[(kk + dk) * 128];
            float4 w1 = *(const float4*)&Wp[(kk + dk) * 128 + 4];
            #pragma unroll
            for (int i = 0; i < 8; ++i) {
                float av = (dk == 0) ? af[i].x : (dk == 1) ? af[i].y
                         : (dk == 2) ? af[i].z : af[i].w;
                acc[i][0] += av * w0.x; acc[i][1] += av * w0.y;
                acc[i][2] += av * w0.z; acc[i][3] += av * w0.w;
                acc[i][4] += av * w1.x; acc[i][5] += av * w1.y;
                acc[i][6] += av * w1.z; acc[i][7] += av * w1.w;
            }
        }
    }
}

// Per layer: [t = relu(in@Wa+ba)] ; x = relu(t@Wb+bb) ; y = x@Wjk(+bjk) ; pooled += y
template<bool DO_A, bool LASTB, bool WRITE_X>
__global__ __launch_bounds__(128) void mlp_fused(
        const float* __restrict__ in,
        const float* __restrict__ Wa, const float* __restrict__ ba,
        const float* __restrict__ Wb, const float* __restrict__ bb,
        const float* __restrict__ Wjk, const float* __restrict__ bjk,
        const int* __restrict__ batch,
        float* __restrict__ xout, float* __restrict__ pooled, int n)
{
    __shared__ float a_lds[64][132];   // 33 KB -> 4 blocks/CU
    int t = threadIdx.x, tx = t & 15, ty = t >> 4;   // tx 0..15, ty 0..7
    int row0 = blockIdx.x * 64;
    int c0 = tx * 8, r0 = ty * 8;
    float acc[8][8];

    // stage input rows (zero-fill invalid rows), swizzled
    #pragma unroll
    for (int it = 0; it < 16; ++it) {
        int l = t + 128 * it;
        int r = l >> 5, c4 = (l & 31) * 4;
        int gr = row0 + r;
        float4 av = make_float4(0.f, 0.f, 0.f, 0.f);
        if (gr < n) av = *(const float4*)&in[gr * 128 + c4];
        *(float4*)&a_lds[r][c4 ^ swz(r)] = av;
    }
    __syncthreads();

    if (DO_A) {
        gemm_core_g(Wa, a_lds, tx, ty, acc);
        __syncthreads();   // all a_lds reads done
        float bv[8];
        #pragma unroll
        for (int j = 0; j < 8; ++j) bv[j] = ba[c0 + j];
        #pragma unroll
        for (int i = 0; i < 8; ++i) {
            int r = r0 + i, gr = row0 + r;
            float o[8];
            #pragma unroll
            for (int j = 0; j < 8; ++j)
                o[j] = (gr < n) ? fmaxf(acc[i][j] + bv[j], 0.f) : 0.f;
            int s = swz(r);
            *(float4*)&a_lds[r][c0 ^ s]       = make_float4(o[0], o[1], o[2], o[3]);
            *(float4*)&a_lds[r][(c0 + 4) ^ s] = make_float4(o[4], o[5], o[6], o[7]);
        }
        __syncthreads();
    }

    gemm_core_g(Wb, a_lds, tx, ty, acc);
    __syncthreads();
    {
        float bv[8];
        #pragma unroll
        for (int j = 0; j < 8; ++j) bv[j] = bb[c0 + j];
        #pragma unroll
        for (int i = 0; i < 8; ++i) {
            int r = r0 + i, gr = row0 + r;
            float o[8];
            #pragma unroll
            for (int j = 0; j < 8; ++j)
                o[j] = (gr < n) ? fmaxf(acc[i][j] + bv[j], 0.f) : 0.f;
            int s = swz(r);
            *(float4*)&a_lds[r][c0 ^ s]       = make_float4(o[0], o[1], o[2], o[3]);
            *(float4*)&a_lds[r][(c0 + 4) ^ s] = make_float4(o[4], o[5], o[6], o[7]);
            if (WRITE_X && gr < n) {
                *(float4*)&xout[gr * 128 + c0]     = make_float4(o[0], o[1], o[2], o[3]);
                *(float4*)&xout[gr * 128 + c0 + 4] = make_float4(o[4], o[5], o[6], o[7]);
            }
        }
    }
    __syncthreads();

    gemm_core_g(Wjk, a_lds, tx, ty, acc);
    __syncthreads();   // a_lds now free for reduction scratch

    if (LASTB) {
        float bv[8];
        #pragma unroll
        for (int j = 0; j < 8; ++j) bv[j] = bjk[c0 + j];
        #pragma unroll
        for (int i = 0; i < 8; ++i) {
            int gr = row0 + r0 + i;
            if (gr < n) {
                #pragma unroll
                for (int j = 0; j < 8; ++j) acc[i][j] += bv[j];
            }
        }
    }

    int row_last = row0 + 63; if (row_last > n - 1) row_last = n - 1;
    int g_first = batch[row0];
    int g_last  = batch[row_last];
    float* red = &a_lds[0][0];   // 1024 floats scratch
    if (g_first == g_last) {
        float s[8];
        #pragma unroll
        for (int j = 0; j < 8; ++j) {
            s[j] = 0.f;
            #pragma unroll
            for (int i = 0; i < 8; ++i) s[j] += acc[i][j];   // invalid rows are exact zeros
        }
        #pragma unroll
        for (int j = 0; j < 8; ++j) red[ty * 128 + c0 + j] = s[j];
        __syncthreads();
        float tot = 0.f;
        #pragma unroll
        for (int g = 0; g < 8; ++g) tot += red[g * 128 + t];
        atomicAdd(&pooled[g_first * 128 + t], tot);
    } else {
        #pragma unroll
        for (int i = 0; i < 8; ++i) {
            int gr = row0 + r0 + i;
            if (gr < n) {
                int g = batch[gr];
                #pragma unroll
                for (int j = 0; j < 8; ++j)
                    atomicAdd(&pooled[g * 128 + c0 + j], acc[i][j]);
            }
        }
    }
}

// ---------------- classifier ----------------

__global__ __launch_bounds__(256) void classifier(const float* __restrict__ pooled,
        const float* __restrict__ Wc1, const float* __restrict__ bc1,
        const float* __restrict__ gamma, const float* __restrict__ beta,
        const float* __restrict__ rmean, const float* __restrict__ rvar,
        const float* __restrict__ Wc2, const float* __restrict__ bc2,
        float* __restrict__ out) {
    int g = blockIdx.x, t = threadIdx.x;
    __shared__ float p[128];
    __shared__ float r0[256], r1[256];
    if (t < 128) p[t] = pooled[g * 128 + t];
    __syncthreads();
    float acc = bc1[t];
    #pragma unroll 8
    for (int k = 0; k < 128; ++k) acc += p[k] * Wc1[k * 256 + t];
    float z = (acc - rmean[t]) * rsqrtf(rvar[t] + 1e-5f) * gamma[t] + beta[t];
    z = fmaxf(z, 0.f);
    r0[t] = z * Wc2[t * 2 + 0];
    r1[t] = z * Wc2[t * 2 + 1];
    __syncthreads();
    for (int s = 128; s > 0; s >>= 1) {
        if (t < s) { r0[t] += r0[t + s]; r1[t] += r1[t + s]; }
        __syncthreads();
    }
    if (t == 0) {
        out[g * 2 + 0] = r0[0] + bc2[0];
        out[g * 2 + 1] = r1[0] + bc2[1];
    }
}

// ---------------- launch ----------------

static inline size_t al256(size_t x) { return (x + 255) & ~size_t(255); }

extern "C" void kernel_launch(void* const* d_in, const int* in_sizes, int n_in,
                              void* d_out, int out_size, void* d_ws, size_t ws_size,
                              hipStream_t stream) {
    const float* x    = (const float*)d_in[0];
    const int*   ei   = (const int*)  d_in[1];
    const int*   batch= (const int*)  d_in[3];
    const float* W0a = (const float*)d_in[4];  const float* b0a = (const float*)d_in[5];
    const float* W0b = (const float*)d_in[6];  const float* b0b = (const float*)d_in[7];
    const float* W1a = (const float*)d_in[8];  const float* b1a = (const float*)d_in[9];
    const float* W1b = (const float*)d_in[10]; const float* b1b = (const float*)d_in[11];
    const float* W2a = (const float*)d_in[12]; const float* b2a = (const float*)d_in[13];
    const float* W2b = (const float*)d_in[14]; const float* b2b = (const float*)d_in[15];
    const float* Wjk = (const float*)d_in[16]; const float* bjk = (const float*)d_in[17];
    const float* Wc1 = (const float*)d_in[18]; const float* bc1 = (const float*)d_in[19];
    const float* gamma=(const float*)d_in[20]; const float* beta= (const float*)d_in[21];
    const float* rmean=(const float*)d_in[22]; const float* rvar= (const float*)d_in[23];
    const float* Wc2 = (const float*)d_in[24]; const float* bc2 = (const float*)d_in[25];
    float* out = (float*)d_out;

    const int N = NN, E = EE, B = BB;

    char* w = (char*)d_ws;
    size_t off = 0;
    int* deg    = (int*)(w + off); off = al256(off + (size_t)N * 4);
    int* rowptr = (int*)(w + off); off = al256(off + (size_t)(N + 1) * 4);
    int* cursor = (int*)(w + off); off = al256(off + (size_t)N * 4);
    int* colarr = (int*)(w + off); off = al256(off + (size_t)E * 4);
    int* bsum   = (int*)(w + off); off = al256(off + 1024 * 4);
    float* h0   = (float*)(w + off); off = al256(off + (size_t)N * 8 * 4);
    float* SA   = (float*)(w + off); off = al256(off + (size_t)N * 128 * 4);
    float* SB   = (float*)(w + off); off = al256(off + (size_t)N * 128 * 4);
    float* XC   = (float*)(w + off); off = al256(off + (size_t)N * 128 * 4);
    float* pooled = (float*)(w + off); off = al256(off + (size_t)B * 128 * 4);

    hipMemsetAsync(deg, 0, (size_t)N * 4, stream);
    hipMemsetAsync(pooled, 0, (size_t)B * 128 * 4, stream);

    int nb = (N + 1023) / 1024;   // 98

    count_deg<<<(E + 255) / 256, 256, 0, stream>>>(ei, deg, E);
    scan_partial<<<nb, 256, 0, stream>>>(deg, bsum, N);
    scan_bsum<<<1, 256, 0, stream>>>(bsum, nb);
    scan_apply<<<nb, 256, 0, stream>>>(deg, bsum, rowptr, cursor, N, E);
    fill_csr<<<(E + 255) / 256, 256, 0, stream>>>(ei, cursor, colarr, E);

    int gLin = (N + 63) / 64;   // 1563

    // Layer 0: agg(d=7) -> lin7 (= t0) -> fused [x1; jk0; pool]
    agg7<<<(N + 31) / 32, 256, 0, stream>>>(x, rowptr, colarr, h0, N);
    lin7<<<(N + 7) / 8, 256, 0, stream>>>(h0, W0a, b0a, SB, N);
    mlp_fused<false, false, true><<<gLin, 128, 0, stream>>>(
        SB, nullptr, nullptr, W0b, b0b, Wjk, nullptr, batch, XC, pooled, N);

    // Layer 1
    agg128<<<(N + 1) / 2, 256, 0, stream>>>(XC, rowptr, colarr, SA, N);
    mlp_fused<true, false, true><<<gLin, 128, 0, stream>>>(
        SA, W1a, b1a, W1b, b1b, Wjk + 128 * 128, nullptr, batch, XC, pooled, N);

    // Layer 2 (x3 never materialized)
    agg128<<<(N + 1) / 2, 256, 0, stream>>>(XC, rowptr, colarr, SA, N);
    mlp_fused<true, true, false><<<gLin, 128, 0, stream>>>(
        SA, W2a, b2a, W2b, b2b, Wjk + 256 * 128, bjk, batch, nullptr, pooled, N);

    classifier<<<B, 256, 0, stream>>>(pooled, Wc1, bc1, gamma, beta,
                                      rmean, rvar, Wc2, bc2, out);
}